// Round 2
// baseline (283.647 us; speedup 1.0000x reference)
//
#include <hip/hip_runtime.h>

// Problem: B=2, S=2048, D_IN=1024, H=16, HD=64 causal MHA.
// I/O is fp32 (reference dtype); internal compute bf16 MFMA (threshold = 2%
// of ref absmax accommodates bf16).
// Pipeline: convx_k (x fp32 -> xb bf16) ; wtrans_k (W fp32 -> Wt bf16
// [mat,h,e,d]) ; proj_k (Q,K bf16 [b,h,s,e], V bf16 transposed [b,h,e,s],
// softmax scale*log2e folded into Q) ; attn_k (flash, MFMA, fp32 out).

#define DI   1024
#define HD   64
#define NH   16
#define SEQ  2048
#define NB   2

typedef unsigned short u16;
typedef unsigned short us8 __attribute__((ext_vector_type(8)));
typedef unsigned short us4 __attribute__((ext_vector_type(4)));
typedef short bf8 __attribute__((ext_vector_type(8)));   // 8 x bf16 (4 VGPRs)
typedef float f4 __attribute__((ext_vector_type(4)));

#define MFMA16(a, b, c) __builtin_amdgcn_mfma_f32_16x16x32_bf16((a), (b), (c), 0, 0, 0)

__device__ __forceinline__ u16 f2bf(float f) {  // RNE fp32 -> bf16
  unsigned u = __float_as_uint(f);
  u += 0x7fffu + ((u >> 16) & 1u);
  return (u16)(u >> 16);
}

// ---------------- x: fp32 -> bf16 ----------------
__global__ __launch_bounds__(256) void convx_k(const float* __restrict__ x,
                                               u16* __restrict__ xb) {
  const int i = (blockIdx.x * 256 + threadIdx.x) * 8;
  float4 v0 = *(const float4*)(x + i);
  float4 v1 = *(const float4*)(x + i + 4);
  us8 o;
  o[0] = f2bf(v0.x); o[1] = f2bf(v0.y); o[2] = f2bf(v0.z); o[3] = f2bf(v0.w);
  o[4] = f2bf(v1.x); o[5] = f2bf(v1.y); o[6] = f2bf(v1.z); o[7] = f2bf(v1.w);
  *(us8*)(xb + i) = o;
}

// ---------------- W transpose: W[mat,h,d,e] fp32 -> Wt[mat,h,e,d] bf16 -----
__global__ __launch_bounds__(256) void wtrans_k(const float* __restrict__ Wq,
                                                const float* __restrict__ Wk,
                                                const float* __restrict__ Wv,
                                                u16* __restrict__ Wt) {
  __shared__ __align__(16) u16 tile[64][72];
  const int mh = blockIdx.x;          // mat*16 + h, 0..47
  const int d0 = blockIdx.y * 64;     // 0..960
  const int mat = mh >> 4, h = mh & 15;
  const float* W = (mat == 0 ? Wq : (mat == 1 ? Wk : Wv)) + (size_t)h * DI * HD;
  const int t = threadIdx.x;
  {
    const int r = t >> 2, c = (t & 3) * 16;
    const float* src = W + (size_t)(d0 + r) * HD + c;
    #pragma unroll
    for (int j = 0; j < 4; j++) {
      float4 v = *(const float4*)(src + j * 4);
      tile[r][c + j * 4 + 0] = f2bf(v.x);
      tile[r][c + j * 4 + 1] = f2bf(v.y);
      tile[r][c + j * 4 + 2] = f2bf(v.z);
      tile[r][c + j * 4 + 3] = f2bf(v.w);
    }
  }
  __syncthreads();
  {
    const int e = t >> 2, c = (t & 3) * 16;
    __align__(16) u16 tmp[16];
    #pragma unroll
    for (int i = 0; i < 16; i++) tmp[i] = tile[c + i][e];
    u16* dst = Wt + ((size_t)mh * HD + e) * DI + d0 + c;
    *(us8*)dst       = *(us8*)&tmp[0];
    *(us8*)(dst + 8) = *(us8*)&tmp[8];
  }
}

// ---------------- QKV projection GEMM (bf16 in, bf16 out) ----------------
// grid.x = M-tile (32 of 128 rows), grid.y = mat*16+h (48). Block 256 = 4 waves.
__global__ __launch_bounds__(256) void proj_k(const u16* __restrict__ x,
                                              const u16* __restrict__ Wt,
                                              u16* __restrict__ Qo,
                                              u16* __restrict__ Ko,
                                              u16* __restrict__ Vo) {
  __shared__ __align__(16) u16 xs[128][72];
  __shared__ __align__(16) u16 wsld[64][72];
  const int m0 = blockIdx.x * 128;
  const int mh = blockIdx.y;
  const int mat = mh >> 4, h = mh & 15;
  const int tid = threadIdx.x;
  const int w = tid >> 6, lane = tid & 63;
  const int l15 = lane & 15, quad = lane >> 4;
  const u16* Wb = Wt + (size_t)mh * HD * DI;

  f4 acc[2][4];
  #pragma unroll
  for (int i = 0; i < 2; i++)
    #pragma unroll
    for (int j = 0; j < 4; j++) {
      f4 z = {0.f, 0.f, 0.f, 0.f};
      acc[i][j] = z;
    }

  for (int k0 = 0; k0 < DI; k0 += 64) {
    #pragma unroll
    for (int i = 0; i < 4; i++) {           // x tile: 128x64
      int c = tid + i * 256;
      int row = c >> 3, ch = c & 7;
      *(us8*)&xs[row][ch * 8] = *(const us8*)(x + (size_t)(m0 + row) * DI + k0 + ch * 8);
    }
    #pragma unroll
    for (int i = 0; i < 2; i++) {           // Wt tile: 64x64
      int c = tid + i * 256;
      int e = c >> 3, ch = c & 7;
      *(us8*)&wsld[e][ch * 8] = *(const us8*)(Wb + (size_t)e * DI + k0 + ch * 8);
    }
    __syncthreads();
    #pragma unroll
    for (int ks = 0; ks < 64; ks += 32) {
      bf8 a0 = *(const bf8*)&xs[w * 32 + l15][ks + quad * 8];
      bf8 a1 = *(const bf8*)&xs[w * 32 + 16 + l15][ks + quad * 8];
      #pragma unroll
      for (int n = 0; n < 4; n++) {
        bf8 bb = *(const bf8*)&wsld[n * 16 + l15][ks + quad * 8];
        acc[0][n] = MFMA16(a0, bb, acc[0][n]);
        acc[1][n] = MFMA16(a1, bb, acc[1][n]);
      }
    }
    __syncthreads();
  }

  // C layout (verified m89/m91): col = lane&15, row = quad*4 + reg.
  const float qscale = 0.125f * 1.44269504088896340736f;  // 1/sqrt(64) * log2(e)
  #pragma unroll
  for (int mi = 0; mi < 2; mi++) {
    const int mbase = m0 + w * 32 + mi * 16 + quad * 4;
    const int b = mbase >> 11;
    const int sbase = mbase & (SEQ - 1);
    if (mat == 2) {
      // V transposed: Vo[((b*NH+h)*HD + e)*SEQ + s]; 4 regs = 4 consecutive s.
      #pragma unroll
      for (int n = 0; n < 4; n++) {
        const int e = n * 16 + l15;
        __align__(8) u16 pk[4];
        #pragma unroll
        for (int r = 0; r < 4; r++) pk[r] = f2bf(acc[mi][n][r]);
        u16* dst = Vo + (((size_t)b * NH + h) * HD + e) * SEQ + sbase;
        *(us4*)dst = *(us4*)pk;
      }
    } else {
      u16* O = (mat == 0) ? Qo : Ko;
      const float sc = (mat == 0) ? qscale : 1.0f;
      #pragma unroll
      for (int n = 0; n < 4; n++) {
        const int e = n * 16 + l15;
        #pragma unroll
        for (int r = 0; r < 4; r++)
          O[(((size_t)b * NH + h) * SEQ + sbase + r) * HD + e] = f2bf(acc[mi][n][r] * sc);
      }
    }
  }
}

// ---------------- Flash attention (bf16 in, fp32 out) ----------------
// grid.x = q-tile (reversed: heavy tiles first), grid.y = b*16+h.
// Block 256 = 4 waves; wave w owns q rows [q0+w*16, q0+w*16+16).
__global__ __launch_bounds__(256) void attn_k(const u16* __restrict__ Qo,
                                              const u16* __restrict__ Ko,
                                              const u16* __restrict__ Vo,
                                              float* __restrict__ out) {
  __shared__ __align__(16) u16 Ks[64][72];
  __shared__ __align__(16) u16 Vs[64][72];      // Vt tile: [e][t]
  __shared__ __align__(16) u16 Ps[4][16][72];   // per-wave P round-trip
  const int qt = 31 - (int)blockIdx.x;
  const int bh = blockIdx.y;
  const int b = bh >> 4, h = bh & 15;
  const int q0 = qt * 64;
  const int tid = threadIdx.x;
  const int w = tid >> 6, lane = tid & 63;
  const int l15 = lane & 15, quad = lane >> 4;

  const u16* Qb = Qo + (size_t)bh * SEQ * HD;
  const u16* Kb = Ko + (size_t)bh * SEQ * HD;
  const u16* Vb = Vo + (size_t)bh * HD * SEQ;

  // Q A-frags (A[m=lane&15][k=quad*8+j]), held for whole kernel.
  const int qrow_a = q0 + w * 16 + l15;
  bf8 aq0 = *(const bf8*)(Qb + (size_t)qrow_a * HD + quad * 8);
  bf8 aq1 = *(const bf8*)(Qb + (size_t)qrow_a * HD + 32 + quad * 8);

  float m_i[4] = {-1e30f, -1e30f, -1e30f, -1e30f};
  float l_i[4] = {0.f, 0.f, 0.f, 0.f};
  f4 oacc[4];
  #pragma unroll
  for (int i = 0; i < 4; i++) {
    f4 z = {0.f, 0.f, 0.f, 0.f};
    oacc[i] = z;
  }

  const int ntile = qt + 1;
  for (int it = 0; it < ntile; it++) {
    const int t0 = it * 64;
    #pragma unroll
    for (int i = 0; i < 2; i++) {
      int c = tid + i * 256;
      int rr = c >> 3, ch = c & 7;
      *(us8*)&Ks[rr][ch * 8] = *(const us8*)(Kb + (size_t)(t0 + rr) * HD + ch * 8);
      *(us8*)&Vs[rr][ch * 8] = *(const us8*)(Vb + (size_t)rr * SEQ + t0 + ch * 8);
    }
    __syncthreads();

    // S = Q K^T (already in exp2 domain: scale*log2e folded into Q).
    f4 sacc[4];
    #pragma unroll
    for (int n = 0; n < 4; n++) {
      f4 z = {0.f, 0.f, 0.f, 0.f};
      sacc[n] = z;
      bf8 b0 = *(const bf8*)&Ks[n * 16 + l15][quad * 8];
      bf8 b1 = *(const bf8*)&Ks[n * 16 + l15][32 + quad * 8];
      sacc[n] = MFMA16(aq0, b0, sacc[n]);
      sacc[n] = MFMA16(aq1, b1, sacc[n]);
    }

    // Causal mask + online softmax. Lane's row r = q-row quad*4+r; cols across
    // the 16 lanes of the quad (and 4 n-frags).
    const int qbase = q0 + w * 16 + quad * 4;
    float rm[4] = {-1e30f, -1e30f, -1e30f, -1e30f};
    #pragma unroll
    for (int n = 0; n < 4; n++) {
      const int tcol = t0 + n * 16 + l15;
      #pragma unroll
      for (int r = 0; r < 4; r++) {
        float s = (tcol <= qbase + r) ? sacc[n][r] : -1e30f;
        sacc[n][r] = s;
        rm[r] = fmaxf(rm[r], s);
      }
    }
    #pragma unroll
    for (int r = 0; r < 4; r++) {
      #pragma unroll
      for (int d = 1; d < 16; d <<= 1) rm[r] = fmaxf(rm[r], __shfl_xor(rm[r], d, 64));
    }
    float alpha[4];
    #pragma unroll
    for (int r = 0; r < 4; r++) {
      float mn = fmaxf(m_i[r], rm[r]);
      alpha[r] = exp2f(m_i[r] - mn);
      m_i[r] = mn;
    }
    float rs[4] = {0.f, 0.f, 0.f, 0.f};
    #pragma unroll
    for (int n = 0; n < 4; n++)
      #pragma unroll
      for (int r = 0; r < 4; r++) {
        float p = exp2f(sacc[n][r] - m_i[r]);   // masked: exp2(-1e30) = 0
        sacc[n][r] = p;
        rs[r] += p;
      }
    #pragma unroll
    for (int r = 0; r < 4; r++) {
      #pragma unroll
      for (int d = 1; d < 16; d <<= 1) rs[r] += __shfl_xor(rs[r], d, 64);
      l_i[r] = alpha[r] * l_i[r] + rs[r];
    }
    #pragma unroll
    for (int ne = 0; ne < 4; ne++)
      #pragma unroll
      for (int r = 0; r < 4; r++) oacc[ne][r] *= alpha[r];

    // P: C-layout -> LDS -> A-layout (per-wave region, in-order DS pipe).
    #pragma unroll
    for (int n = 0; n < 4; n++)
      #pragma unroll
      for (int r = 0; r < 4; r++)
        Ps[w][quad * 4 + r][n * 16 + l15] = f2bf(sacc[n][r]);

    bf8 pa0 = *(const bf8*)&Ps[w][l15][quad * 8];
    bf8 pa1 = *(const bf8*)&Ps[w][l15][32 + quad * 8];
    #pragma unroll
    for (int ne = 0; ne < 4; ne++) {
      bf8 v0 = *(const bf8*)&Vs[ne * 16 + l15][quad * 8];
      bf8 v1 = *(const bf8*)&Vs[ne * 16 + l15][32 + quad * 8];
      oacc[ne] = MFMA16(pa0, v0, oacc[ne]);
      oacc[ne] = MFMA16(pa1, v1, oacc[ne]);
    }
    __syncthreads();
  }

  #pragma unroll
  for (int r = 0; r < 4; r++) {
    const float inv = 1.0f / l_i[r];
    const int q = q0 + w * 16 + quad * 4 + r;
    #pragma unroll
    for (int ne = 0; ne < 4; ne++)
      out[((size_t)b * SEQ + q) * (NH * HD) + h * HD + ne * 16 + l15] =
          oacc[ne][r] * inv;
  }
}

extern "C" void kernel_launch(void* const* d_in, const int* in_sizes, int n_in,
                              void* d_out, int out_size, void* d_ws, size_t ws_size,
                              hipStream_t stream) {
  const float* x  = (const float*)d_in[0];
  const float* Wq = (const float*)d_in[1];
  const float* Wk = (const float*)d_in[2];
  const float* Wv = (const float*)d_in[3];
  float* out = (float*)d_out;

  u16* xb = (u16*)d_ws;                                   // 2*2048*1024 bf16
  u16* Wt = xb + (size_t)NB * SEQ * DI;                   // 3*16*64*1024
  u16* Qo = Wt + (size_t)3 * NH * HD * DI;                // 2*16*2048*64 each
  u16* Ko = Qo + (size_t)NB * NH * SEQ * HD;
  u16* Vo = Ko + (size_t)NB * NH * SEQ * HD;              // total ~39.5 MB

  convx_k<<<dim3(NB * SEQ * DI / 2048), 256, 0, stream>>>(x, xb);
  wtrans_k<<<dim3(48, 16), 256, 0, stream>>>(Wq, Wk, Wv, Wt);
  proj_k<<<dim3(32, 48), 256, 0, stream>>>(xb, Wt, Qo, Ko, Vo);
  attn_k<<<dim3(32, 32), 256, 0, stream>>>(Qo, Ko, Vo, out);
}

// Round 3
// 232.640 us; speedup vs baseline: 1.2193x; 1.2193x over previous
//
#include <hip/hip_runtime.h>

// B=2, S=2048, D_IN=1024, H=16, HD=64 causal MHA. fp32 I/O, bf16 MFMA inside.
// convx_k (x->bf16) ; wtrans_k (W -> Wt[mat,h,e,d] bf16 = B^T layout) ;
// proj_k (fused 4096x3072x1024 GEMM, m97-style global_load_lds staging;
//         Q scaled by 1/8*log2e, V stored transposed [b,h,e,s]) ;
// attn_k (flash, K-tile 128, register-prefetch double stage, fp32 out).

#define DI   1024
#define HD   64
#define NH   16
#define SEQ  2048
#define NB   2

typedef unsigned short u16;
typedef unsigned short us8 __attribute__((ext_vector_type(8)));
typedef unsigned short us4 __attribute__((ext_vector_type(4)));
typedef short bf8 __attribute__((ext_vector_type(8)));   // 8 x bf16
typedef float f4 __attribute__((ext_vector_type(4)));

#define MFMA16(a, b, c) __builtin_amdgcn_mfma_f32_16x16x32_bf16((a), (b), (c), 0, 0, 0)

__device__ __forceinline__ u16 f2bf(float f) {  // RNE fp32 -> bf16
  unsigned u = __float_as_uint(f);
  u += 0x7fffu + ((u >> 16) & 1u);
  return (u16)(u >> 16);
}

// async global->LDS, 16B per lane; LDS dest = wave-uniform base + lane*16.
__device__ __forceinline__ void async16(const u16* g, u16* l) {
  __builtin_amdgcn_global_load_lds((const __attribute__((address_space(1))) void*)g,
                                   (__attribute__((address_space(3))) void*)l,
                                   16, 0, 0);
}

// ---------------- x: fp32 -> bf16 ----------------
__global__ __launch_bounds__(256) void convx_k(const float* __restrict__ x,
                                               u16* __restrict__ xb) {
  const int i = (blockIdx.x * 256 + threadIdx.x) * 8;
  float4 v0 = *(const float4*)(x + i);
  float4 v1 = *(const float4*)(x + i + 4);
  us8 o;
  o[0] = f2bf(v0.x); o[1] = f2bf(v0.y); o[2] = f2bf(v0.z); o[3] = f2bf(v0.w);
  o[4] = f2bf(v1.x); o[5] = f2bf(v1.y); o[6] = f2bf(v1.z); o[7] = f2bf(v1.w);
  *(us8*)(xb + i) = o;
}

// ------------- W[mat,h,d,e] fp32 -> Wt[mat,h,e,d] bf16 (B^T layout) -------
__global__ __launch_bounds__(256) void wtrans_k(const float* __restrict__ Wq,
                                                const float* __restrict__ Wk,
                                                const float* __restrict__ Wv,
                                                u16* __restrict__ Wt) {
  __shared__ __align__(16) u16 tile[64][72];
  const int mh = blockIdx.x;          // mat*16 + h
  const int d0 = blockIdx.y * 64;
  const int mat = mh >> 4, h = mh & 15;
  const float* W = (mat == 0 ? Wq : (mat == 1 ? Wk : Wv)) + (size_t)h * DI * HD;
  const int t = threadIdx.x;
  {
    const int r = t >> 2, c = (t & 3) * 16;
    const float* src = W + (size_t)(d0 + r) * HD + c;
    #pragma unroll
    for (int j = 0; j < 4; j++) {
      float4 v = *(const float4*)(src + j * 4);
      tile[r][c + j * 4 + 0] = f2bf(v.x);
      tile[r][c + j * 4 + 1] = f2bf(v.y);
      tile[r][c + j * 4 + 2] = f2bf(v.z);
      tile[r][c + j * 4 + 3] = f2bf(v.w);
    }
  }
  __syncthreads();
  {
    const int e = t >> 2, c = (t & 3) * 16;
    __align__(16) u16 tmp[16];
    #pragma unroll
    for (int i = 0; i < 16; i++) tmp[i] = tile[c + i][e];
    u16* dst = Wt + ((size_t)mh * HD + e) * DI + d0 + c;
    *(us8*)dst       = *(us8*)&tmp[0];
    *(us8*)(dst + 8) = *(us8*)&tmp[8];
  }
}

// ---------------- fused QKV GEMM: [4096x1024] x [1024x3072] ----------------
// 128x128 tile, 4 waves (2x2 of 64x64), BK=64, global_load_lds staging.
// grid (32, 24); n0 block stays within one mat (1024 % 128 == 0).
__global__ __launch_bounds__(256) void proj_k(const u16* __restrict__ x,
                                              const u16* __restrict__ Wt,
                                              u16* __restrict__ Qo,
                                              u16* __restrict__ Ko,
                                              u16* __restrict__ Vo) {
  __shared__ __align__(16) u16 xs[128 * 64];   // unpadded: global_load_lds
  __shared__ __align__(16) u16 ws[128 * 64];
  const int m0 = blockIdx.x * 128, n0 = blockIdx.y * 128;
  const int tid = threadIdx.x, w = tid >> 6, lane = tid & 63;
  const int l15 = lane & 15, quad = lane >> 4;
  const int lrow = lane >> 3, lch = lane & 7;   // 8 lanes x 16B per row

  f4 acc[4][4];
  #pragma unroll
  for (int i = 0; i < 4; i++)
    #pragma unroll
    for (int j = 0; j < 4; j++) {
      f4 z = {0.f, 0.f, 0.f, 0.f};
      acc[i][j] = z;
    }

  const u16* xg = x  + (size_t)(m0 + lrow) * DI + lch * 8;
  const u16* wg = Wt + (size_t)(n0 + lrow) * DI + lch * 8;

  for (int k0 = 0; k0 < DI; k0 += 64) {
    #pragma unroll
    for (int i = 0; i < 4; i++) {
      const int r0 = i * 32 + w * 8;
      async16(xg + (size_t)r0 * DI + k0, &xs[r0 * 64]);
      async16(wg + (size_t)r0 * DI + k0, &ws[r0 * 64]);
    }
    __syncthreads();
    #pragma unroll
    for (int ks = 0; ks < 64; ks += 32) {
      bf8 af[4], bfr[4];
      #pragma unroll
      for (int i = 0; i < 4; i++)
        af[i] = *(const bf8*)&xs[((w >> 1) * 64 + i * 16 + l15) * 64 + ks + quad * 8];
      #pragma unroll
      for (int i = 0; i < 4; i++)
        bfr[i] = *(const bf8*)&ws[((w & 1) * 64 + i * 16 + l15) * 64 + ks + quad * 8];
      #pragma unroll
      for (int mi = 0; mi < 4; mi++)
        #pragma unroll
        for (int ni = 0; ni < 4; ni++)
          acc[mi][ni] = MFMA16(af[mi], bfr[ni], acc[mi][ni]);
    }
    __syncthreads();
  }

  // C layout: col = lane&15, row = quad*4 + reg.
  const int mat = n0 >> 10;                       // uniform per block
  const int nf0 = n0 + (w & 1) * 64;
  const float qscale = 0.125f * 1.44269504088896340736f;
  #pragma unroll
  for (int mi = 0; mi < 4; mi++) {
    const int mrow = m0 + (w >> 1) * 64 + mi * 16 + quad * 4;
    const int b = mrow >> 11, sb = mrow & (SEQ - 1);
    #pragma unroll
    for (int ni = 0; ni < 4; ni++) {
      const int nf = nf0 + ni * 16;
      const int h = (nf >> 6) & 15;
      const int e = (nf & 63) + l15;
      if (mat == 2) {
        __align__(8) u16 pk[4];
        #pragma unroll
        for (int r = 0; r < 4; r++) pk[r] = f2bf(acc[mi][ni][r]);
        *(us4*)(Vo + (((size_t)b * NH + h) * HD + e) * SEQ + sb) = *(us4*)pk;
      } else {
        u16* O = mat ? Ko : Qo;
        const float sc = mat ? 1.0f : qscale;
        #pragma unroll
        for (int r = 0; r < 4; r++)
          O[(((size_t)b * NH + h) * SEQ + sb + r) * HD + e] = f2bf(acc[mi][ni][r] * sc);
      }
    }
  }
}

// ---------------- flash attention, K-tile 128, reg-prefetch ----------------
// grid (32 qtiles reversed, 32 bh); 4 waves, wave w: q rows [q0+w*16, +16).
__global__ __launch_bounds__(256) void attn_k(const u16* __restrict__ Qo,
                                              const u16* __restrict__ Ko,
                                              const u16* __restrict__ Vo,
                                              float* __restrict__ out) {
  __shared__ __align__(16) u16 Ks[128][72];     // [t][e]
  __shared__ __align__(16) u16 Vs[64][136];     // [e][t]
  __shared__ __align__(16) u16 Ps[4][16][136];  // per-wave P round-trip
  const int qt = 31 - (int)blockIdx.x;
  const int bh = blockIdx.y;
  const int b = bh >> 4, h = bh & 15;
  const int q0 = qt * 64;
  const int tid = threadIdx.x, w = tid >> 6, lane = tid & 63;
  const int l15 = lane & 15, quad = lane >> 4;

  const u16* Qb = Qo + (size_t)bh * SEQ * HD;
  const u16* Kb = Ko + (size_t)bh * SEQ * HD;
  const u16* Vb = Vo + (size_t)bh * HD * SEQ;

  const int qrow = q0 + w * 16 + l15;
  bf8 aq0 = *(const bf8*)(Qb + (size_t)qrow * HD + quad * 8);
  bf8 aq1 = *(const bf8*)(Qb + (size_t)qrow * HD + 32 + quad * 8);

  float m_i[4] = {-1e30f, -1e30f, -1e30f, -1e30f};
  float l_i[4] = {0.f, 0.f, 0.f, 0.f};
  f4 oacc[4];
  #pragma unroll
  for (int i = 0; i < 4; i++) {
    f4 z = {0.f, 0.f, 0.f, 0.f};
    oacc[i] = z;
  }

  const int niter = qt / 2 + 1;
  // staging: K tile 128x64 (1024 us8), V tile 64x128 (1024 us8)
  const int krow = tid >> 3, kch = tid & 7;     // + i*32 rows
  const int vrow = tid >> 4, vch = tid & 15;    // + i*16 rows
  us8 kreg[4], vreg[4];
  #pragma unroll
  for (int i = 0; i < 4; i++) {
    kreg[i] = *(const us8*)(Kb + (size_t)(krow + i * 32) * HD + kch * 8);
    vreg[i] = *(const us8*)(Vb + (size_t)(vrow + i * 16) * SEQ + vch * 8);
  }

  for (int it = 0; it < niter; it++) {
    #pragma unroll
    for (int i = 0; i < 4; i++) {
      *(us8*)&Ks[krow + i * 32][kch * 8] = kreg[i];
      *(us8*)&Vs[vrow + i * 16][vch * 8] = vreg[i];
    }
    __syncthreads();
    if (it + 1 < niter) {                       // prefetch next tile to regs
      const int t0n = (it + 1) * 128;
      #pragma unroll
      for (int i = 0; i < 4; i++) {
        kreg[i] = *(const us8*)(Kb + (size_t)(t0n + krow + i * 32) * HD + kch * 8);
        vreg[i] = *(const us8*)(Vb + (size_t)(vrow + i * 16) * SEQ + t0n + vch * 8);
      }
    }
    const int t0 = it * 128;

    // S = Q K^T (exp2 domain; scale folded into Q)
    f4 sacc[8];
    #pragma unroll
    for (int n = 0; n < 8; n++) {
      f4 z = {0.f, 0.f, 0.f, 0.f};
      sacc[n] = z;
      bf8 b0 = *(const bf8*)&Ks[n * 16 + l15][quad * 8];
      bf8 b1 = *(const bf8*)&Ks[n * 16 + l15][32 + quad * 8];
      sacc[n] = MFMA16(aq0, b0, sacc[n]);
      sacc[n] = MFMA16(aq1, b1, sacc[n]);
    }

    const int qbase = q0 + w * 16 + quad * 4;
    if (it == niter - 1) {                      // causal mask (last tile only)
      #pragma unroll
      for (int n = 0; n < 8; n++) {
        const int tcol = t0 + n * 16 + l15;
        #pragma unroll
        for (int r = 0; r < 4; r++)
          if (tcol > qbase + r) sacc[n][r] = -1e30f;
      }
    }

    float rm[4] = {-1e30f, -1e30f, -1e30f, -1e30f};
    #pragma unroll
    for (int n = 0; n < 8; n++)
      #pragma unroll
      for (int r = 0; r < 4; r++) rm[r] = fmaxf(rm[r], sacc[n][r]);
    #pragma unroll
    for (int r = 0; r < 4; r++) {
      #pragma unroll
      for (int d = 1; d < 16; d <<= 1) rm[r] = fmaxf(rm[r], __shfl_xor(rm[r], d, 64));
    }
    float alpha[4];
    #pragma unroll
    for (int r = 0; r < 4; r++) {
      float mn = fmaxf(m_i[r], rm[r]);
      alpha[r] = exp2f(m_i[r] - mn);
      m_i[r] = mn;
    }
    float rs[4] = {0.f, 0.f, 0.f, 0.f};
    #pragma unroll
    for (int n = 0; n < 8; n++)
      #pragma unroll
      for (int r = 0; r < 4; r++) {
        float p = exp2f(sacc[n][r] - m_i[r]);
        sacc[n][r] = p;
        rs[r] += p;
      }
    #pragma unroll
    for (int r = 0; r < 4; r++) {
      #pragma unroll
      for (int d = 1; d < 16; d <<= 1) rs[r] += __shfl_xor(rs[r], d, 64);
      l_i[r] = alpha[r] * l_i[r] + rs[r];
    }
    #pragma unroll
    for (int ne = 0; ne < 4; ne++)
      #pragma unroll
      for (int r = 0; r < 4; r++) oacc[ne][r] *= alpha[r];

    // P: C-layout -> LDS -> A-layout (per-wave region)
    #pragma unroll
    for (int n = 0; n < 8; n++)
      #pragma unroll
      for (int r = 0; r < 4; r++)
        Ps[w][quad * 4 + r][n * 16 + l15] = f2bf(sacc[n][r]);

    bf8 pa[4];
    #pragma unroll
    for (int kt = 0; kt < 4; kt++)
      pa[kt] = *(const bf8*)&Ps[w][l15][kt * 32 + quad * 8];
    #pragma unroll
    for (int ne = 0; ne < 4; ne++) {
      #pragma unroll
      for (int kt = 0; kt < 4; kt++) {
        bf8 vv = *(const bf8*)&Vs[ne * 16 + l15][kt * 32 + quad * 8];
        oacc[ne] = MFMA16(pa[kt], vv, oacc[ne]);
      }
    }
    __syncthreads();
  }

  #pragma unroll
  for (int r = 0; r < 4; r++) {
    const float inv = 1.0f / l_i[r];
    const int q = q0 + w * 16 + quad * 4 + r;
    #pragma unroll
    for (int ne = 0; ne < 4; ne++)
      out[((size_t)b * SEQ + q) * (NH * HD) + h * HD + ne * 16 + l15] =
          oacc[ne][r] * inv;
  }
}

extern "C" void kernel_launch(void* const* d_in, const int* in_sizes, int n_in,
                              void* d_out, int out_size, void* d_ws, size_t ws_size,
                              hipStream_t stream) {
  const float* x  = (const float*)d_in[0];
  const float* Wq = (const float*)d_in[1];
  const float* Wk = (const float*)d_in[2];
  const float* Wv = (const float*)d_in[3];
  float* out = (float*)d_out;

  u16* xb = (u16*)d_ws;
  u16* Wt = xb + (size_t)NB * SEQ * DI;
  u16* Qo = Wt + (size_t)3 * NH * HD * DI;
  u16* Ko = Qo + (size_t)NB * NH * SEQ * HD;
  u16* Vo = Ko + (size_t)NB * NH * SEQ * HD;

  convx_k<<<dim3(NB * SEQ * DI / 2048), 256, 0, stream>>>(x, xb);
  wtrans_k<<<dim3(48, 16), 256, 0, stream>>>(Wq, Wk, Wv, Wt);
  proj_k<<<dim3(32, 24), 256, 0, stream>>>(xb, Wt, Qo, Ko, Vo);
  attn_k<<<dim3(32, 32), 256, 0, stream>>>(Qo, Ko, Vo, out);
}